// Round 1
// baseline (814.439 us; speedup 1.0000x reference)
//
#include <hip/hip_runtime.h>

// OEQTensorProduct: Z=262144, MUL=64.
//   mid0[z,u]   = C000*wA[u]*x0[z,u]*y0[z] + C110*wD[u]*dot(x1[z,u,:], y1[z,:])
//   mid1[z,u,k] = C011*wB[u]*x0[z,u]*y1[z,k] + C101*wC[u]*x1[z,u,k]*y0[z]
//   out[:,0:128]        = mid0 @ w0 * 0.125
//   out[:,128+3w+k]     = sum_u w1[u,w]*mid1[z,u,k] * 0.125
// Strategy: bf16 MFMA (16x16x32) for the 4 GEMMs; memory-bound target ~772MB HBM.

typedef __attribute__((ext_vector_type(8))) short bf16x8;
typedef __attribute__((ext_vector_type(4))) float f32x4;

__device__ __forceinline__ unsigned short f2bf(float f) {
    union { float f; unsigned u; } v; v.f = f;
    unsigned u = v.u;
    return (unsigned short)((u + 0x7FFFu + ((u >> 16) & 1u)) >> 16);  // RNE
}

__global__ __launch_bounds__(256, 4) void oeq_kernel(
    const float* __restrict__ x, const float* __restrict__ y,
    const float* __restrict__ tpw, const float* __restrict__ w0,
    const float* __restrict__ w1, float* __restrict__ out)
{
    // mid[g][z][u], g=0: mid0, g=1..3: mid1_k ; stride 72 (pad) keeps b128 reads cheap
    __shared__ __align__(16) unsigned short mid[4][64][72];

    const int t    = threadIdx.x;
    const int lane = t & 63;
    const int wv   = t >> 6;              // wave id == GEMM id
    const long zbase = (long)blockIdx.x * 64;

    // ---- B fragments for this wave's GEMM, pre-scaled by 0.125 (exact) ----
    // B[k][n]: lane holds k = ks*32 + (lane>>4)*8 + j, n = nt*16 + (lane&15)
    const float* W = (wv == 0) ? w0 : w1;
    const int bk = (lane >> 4) * 8;
    const int bn = lane & 15;
    bf16x8 bfrag[8][2];
#pragma unroll
    for (int nt = 0; nt < 8; nt++) {
#pragma unroll
        for (int ks = 0; ks < 2; ks++) {
            const float* p = W + (ks * 32 + bk) * 128 + nt * 16 + bn;
            bf16x8 f;
#pragma unroll
            for (int j = 0; j < 8; j++) f[j] = (short)f2bf(0.125f * p[j * 128]);
            bfrag[nt][ks] = f;
        }
    }

    // ---- producer: wave wv computes mids for z rows [wv*16, wv*16+16), lane = u ----
    const float aW = 0.7071067811865476f * tpw[lane];        // C000*wA
    const float bW = 0.7071067811865476f * tpw[64 + lane];   // C011*wB
    const float cW = 0.7071067811865476f * tpw[128 + lane];  // C101*wC
    const float dW = 0.4082482904638631f * tpw[192 + lane];  // C110*wD
#pragma unroll 4
    for (int zi = 0; zi < 16; zi++) {
        const int zl = wv * 16 + zi;
        const long z = zbase + zl;
        const float* xp = x + z * 256;
        const float x0 = xp[lane];
        const float xa = xp[64 + 3 * lane];
        const float xb = xp[65 + 3 * lane];
        const float xc = xp[66 + 3 * lane];
        const float4 yv = *(const float4*)(y + z * 4);
        const float dot = xa * yv.y + xb * yv.z + xc * yv.w;
        const float bx = bW * x0;
        const float cy = cW * yv.x;
        mid[0][zl][lane] = f2bf(aW * x0 * yv.x + dW * dot);
        mid[1][zl][lane] = f2bf(bx * yv.y + cy * xa);
        mid[2][zl][lane] = f2bf(bx * yv.z + cy * xb);
        mid[3][zl][lane] = f2bf(bx * yv.w + cy * xc);
    }
    __syncthreads();

    // ---- consumer: wave wv runs GEMM wv over 4 z-tiles of 16 rows ----
    // A[m][k]: m = lane&15, k = ks*32 + (lane>>4)*8 + j  (contiguous in LDS row)
    // D: col = lane&15, row = (lane>>4)*4 + r
    const int row4 = (lane >> 4) * 4;
    const int cn   = lane & 15;
#pragma unroll
    for (int zt = 0; zt < 4; zt++) {
        const bf16x8 af0 = *(const bf16x8*)&mid[wv][zt * 16 + cn][row4 * 2];
        const bf16x8 af1 = *(const bf16x8*)&mid[wv][zt * 16 + cn][32 + row4 * 2];
        const long zrow = zbase + zt * 16 + row4;
#pragma unroll
        for (int nt = 0; nt < 8; nt++) {
            f32x4 acc = {0.f, 0.f, 0.f, 0.f};
            acc = __builtin_amdgcn_mfma_f32_16x16x32_bf16(af0, bfrag[nt][0], acc, 0, 0, 0);
            acc = __builtin_amdgcn_mfma_f32_16x16x32_bf16(af1, bfrag[nt][1], acc, 0, 0, 0);
            const int col = (wv == 0) ? (nt * 16 + cn)
                                      : (128 + 3 * (nt * 16 + cn) + (wv - 1));
            float* op = out + zrow * 512 + col;
#pragma unroll
            for (int r = 0; r < 4; r++) op[r * 512] = acc[r];
        }
    }
}

extern "C" void kernel_launch(void* const* d_in, const int* in_sizes, int n_in,
                              void* d_out, int out_size, void* d_ws, size_t ws_size,
                              hipStream_t stream) {
    const float* x   = (const float*)d_in[0];
    const float* y   = (const float*)d_in[1];
    const float* tpw = (const float*)d_in[2];
    const float* w0  = (const float*)d_in[3];
    const float* w1  = (const float*)d_in[4];
    float* out = (float*)d_out;
    const int Z = in_sizes[1] / 4;            // 262144
    dim3 grid(Z / 64), block(256);
    oeq_kernel<<<grid, block, 0, stream>>>(x, y, tpw, w0, w1, out);
}